// Round 1
// baseline (107.750 us; speedup 1.0000x reference)
//
#include <hip/hip_runtime.h>

#define RADIUS 8
#define N 512
#define TR 32                 // output rows per block strip
#define LSTRIDE (N + 1)       // LDS row stride: 513 ≡ 1 (mod 32 banks) → conflict-free

__global__ __launch_bounds__(512, 4)
void box_kernel(const float* __restrict__ in, float* __restrict__ out) {
    __shared__ float tile[TR * LSTRIDE];   // 32 * 513 * 4 B = 64.1 KiB

    const int blk   = blockIdx.x;
    const int img   = blk >> 4;            // 16 strips per 512-row image
    const int strip = blk & 15;
    const int r0    = strip * TR;
    const float* __restrict__ ibase = in  + (size_t)img * N * N;
    float* __restrict__       obase = out + (size_t)img * N * N;
    const int c = threadIdx.x;             // column 0..511

    // ---- Phase 1: vertical zero-padded 17-tap sliding sum, column c ----
    // x[k] holds input row (r0 + k - RADIUS); OOB rows read as 0.
    float x[TR + 2 * RADIUS];
#pragma unroll
    for (int k = 0; k < TR + 2 * RADIUS; ++k) {
        const int row = r0 + k - RADIUS;
        x[k] = (row >= 0 && row < N) ? ibase[(size_t)row * N + c] : 0.0f;
    }
    float vs = 0.0f;
#pragma unroll
    for (int k = 0; k <= 2 * RADIUS; ++k) vs += x[k];   // window for output row r0
#pragma unroll
    for (int i = 0; i < TR; ++i) {
        tile[i * LSTRIDE + c] = vs;                     // banks (i + c) % 32 → 2-way, free
        if (i + 1 < TR) vs += x[i + 2 * RADIUS + 1] - x[i];
    }
    __syncthreads();

    // ---- Phase 2: horizontal zero-padded 17-tap sliding sum within tile rows ----
    const int hrow = threadIdx.x & (TR - 1);   // 0..31
    const int seg  = threadIdx.x >> 5;         // 0..15, 32 cols each
    const int c0   = seg * 32;
    const float* trow = &tile[hrow * LSTRIDE];
    float h[32];
    float hs = 0.0f;
#pragma unroll
    for (int k = -RADIUS; k <= RADIUS; ++k) {  // initial window for col c0
        const int col = c0 + k;
        if (col >= 0 && col < N) hs += trow[col];
    }
#pragma unroll
    for (int j = 0; j < 32; ++j) {
        h[j] = hs;
        const int ac = c0 + j + 1 + RADIUS;
        const int sc = c0 + j - RADIUS;
        const float a = (ac < N) ? trow[ac] : 0.0f;
        const float s = (sc >= 0) ? trow[sc] : 0.0f;
        hs += a - s;
    }
    __syncthreads();

    // write results back into the tile (in-place is safe: all reads completed)
    float* twrow = &tile[hrow * LSTRIDE];
#pragma unroll
    for (int j = 0; j < 32; ++j) twrow[c0 + j] = h[j];
    __syncthreads();

    // ---- Phase 3: coalesced store (2 KiB contiguous per row per wave-pair) ----
#pragma unroll
    for (int i = 0; i < TR; ++i) {
        obase[(size_t)(r0 + i) * N + c] = tile[i * LSTRIDE + c];
    }
}

extern "C" void kernel_launch(void* const* d_in, const int* in_sizes, int n_in,
                              void* d_out, int out_size, void* d_ws, size_t ws_size,
                              hipStream_t stream) {
    const float* in = (const float*)d_in[0];
    float* out = (float*)d_out;
    const int images = 8 * 32;                 // batch * channels
    dim3 grid(images * (N / TR));              // 4096 blocks
    dim3 block(512);
    hipLaunchKernelGGL(box_kernel, grid, block, 0, stream, in, out);
}

// Round 2
// 107.667 us; speedup vs baseline: 1.0008x; 1.0008x over previous
//
#include <hip/hip_runtime.h>

#define RADIUS 8
#define N 512
#define TR 32                 // output rows per block strip
#define LSTRIDE (N + 1)       // LDS row stride: 513 ≡ 1 (mod 32 banks) → conflict-free
#define NXCD 8
#define NWG (8 * 32 * (N / TR))   // 4096 work-groups, divisible by 8

__global__ __launch_bounds__(512, 4)
void box_kernel(const float* __restrict__ in, float* __restrict__ out) {
    __shared__ float tile[TR * LSTRIDE];   // 32 * 513 * 4 B = 64.1 KiB

    // ---- XCD-aware swizzle (T1): HW assigns blockIdx.x round-robin across
    // 8 XCDs; remap so each XCD works a CONTIGUOUS run of strips, making the
    // 16-row vertical halo an L2 hit between temporally-adjacent blocks.
    // NWG % 8 == 0 → this simple form is bijective.
    const int bid = blockIdx.x;
    const int blk = (bid % NXCD) * (NWG / NXCD) + bid / NXCD;

    const int img   = blk >> 4;            // 16 strips per 512-row image
    const int strip = blk & 15;
    const int r0    = strip * TR;
    const float* __restrict__ ibase = in  + (size_t)img * N * N;
    float* __restrict__       obase = out + (size_t)img * N * N;
    const int c = threadIdx.x;             // column 0..511

    // ---- Phase 1: vertical zero-padded 17-tap sliding sum, column c ----
    // x[k] holds input row (r0 + k - RADIUS); OOB rows read as 0.
    float x[TR + 2 * RADIUS];
#pragma unroll
    for (int k = 0; k < TR + 2 * RADIUS; ++k) {
        const int row = r0 + k - RADIUS;
        x[k] = (row >= 0 && row < N) ? ibase[(size_t)row * N + c] : 0.0f;
    }
    float vs = 0.0f;
#pragma unroll
    for (int k = 0; k <= 2 * RADIUS; ++k) vs += x[k];   // window for output row r0
#pragma unroll
    for (int i = 0; i < TR; ++i) {
        tile[i * LSTRIDE + c] = vs;                     // banks (i + c) % 32 → 2-way, free
        if (i + 1 < TR) vs += x[i + 2 * RADIUS + 1] - x[i];
    }
    __syncthreads();

    // ---- Phase 2: horizontal zero-padded 17-tap sliding sum within tile rows ----
    const int hrow = threadIdx.x & (TR - 1);   // 0..31
    const int seg  = threadIdx.x >> 5;         // 0..15, 32 cols each
    const int c0   = seg * 32;
    const float* trow = &tile[hrow * LSTRIDE];
    float h[32];
    float hs = 0.0f;
#pragma unroll
    for (int k = -RADIUS; k <= RADIUS; ++k) {  // initial window for col c0
        const int col = c0 + k;
        if (col >= 0 && col < N) hs += trow[col];
    }
#pragma unroll
    for (int j = 0; j < 32; ++j) {
        h[j] = hs;
        const int ac = c0 + j + 1 + RADIUS;
        const int sc = c0 + j - RADIUS;
        const float a = (ac < N) ? trow[ac] : 0.0f;
        const float s = (sc >= 0) ? trow[sc] : 0.0f;
        hs += a - s;
    }
    __syncthreads();

    // write results back into the tile (in-place is safe: all reads completed)
    float* twrow = &tile[hrow * LSTRIDE];
#pragma unroll
    for (int j = 0; j < 32; ++j) twrow[c0 + j] = h[j];
    __syncthreads();

    // ---- Phase 3: coalesced store (2 KiB contiguous per row) ----
#pragma unroll
    for (int i = 0; i < TR; ++i) {
        obase[(size_t)(r0 + i) * N + c] = tile[i * LSTRIDE + c];
    }
}

extern "C" void kernel_launch(void* const* d_in, const int* in_sizes, int n_in,
                              void* d_out, int out_size, void* d_ws, size_t ws_size,
                              hipStream_t stream) {
    const float* in = (const float*)d_in[0];
    float* out = (float*)d_out;
    dim3 grid(NWG);               // 4096 blocks
    dim3 block(512);
    hipLaunchKernelGGL(box_kernel, grid, block, 0, stream, in, out);
}